// Round 5
// baseline (649.136 us; speedup 1.0000x reference)
//
#include <hip/hip_runtime.h>
#include <hip/hip_bf16.h>
#include <math.h>

typedef __bf16 bf16x8 __attribute__((ext_vector_type(8)));
typedef float f32x4 __attribute__((ext_vector_type(4)));
typedef unsigned int u32x2 __attribute__((ext_vector_type(2)));

__device__ __forceinline__ f32x4 mfma16(bf16x8 a, bf16x8 b, f32x4 c) {
  return __builtin_amdgcn_mfma_f32_16x16x32_bf16(a, b, c, 0, 0, 0);
}

__device__ __forceinline__ float gelu_f(float v) {
  return 0.5f * v * (1.0f + erff(v * 0.70710678118654752f));
}

__device__ __forceinline__ void async16(const void* g, void* l) {
  __builtin_amdgcn_global_load_lds((const __attribute__((address_space(1))) unsigned int*)g,
                                   (__attribute__((address_space(3))) unsigned int*)l, 16, 0, 0);
}

__device__ __forceinline__ unsigned lds_off(const void* p) {
  return (unsigned)(unsigned long long)(const __attribute__((address_space(3))) void*)p;
}

// ---- weight convert + transpose: Wt[n][k] = (bf16) W[k][n];  W is K x N row-major
__global__ void wprep_kernel(const float* __restrict__ W, __bf16* __restrict__ Wt, int K, int N) {
  long i = (long)blockIdx.x * 256 + threadIdx.x;
  if (i >= (long)K * N) return;
  int k = (int)(i % K), n = (int)(i / K);
  Wt[i] = (__bf16)W[(long)k * N + n];
}

__global__ void wprep_qkv_kernel(const float* __restrict__ Wq, const float* __restrict__ Wk,
                                 const float* __restrict__ Wv, __bf16* __restrict__ Wt) {
  long i = (long)blockIdx.x * 256 + threadIdx.x;
  if (i >= 2304L * 768) return;
  int k = (int)(i % 768), n = (int)(i / 768);
  const float* W = (n < 768) ? Wq : (n < 1536) ? Wk : Wv;
  Wt[i] = (__bf16)W[(long)k * 768 + (n % 768)];
}

__global__ void bias_cat_kernel(const float* __restrict__ bq, const float* __restrict__ bk,
                                const float* __restrict__ bv, float* __restrict__ o) {
  int i = blockIdx.x * 256 + threadIdx.x;
  if (i >= 2304) return;
  o[i] = (i < 768) ? bq[i] : (i < 1536) ? bk[i - 768] : bv[i - 1536];
}

// ---- layernorm: fp32 in (rows x 768), bf16 out. One block (256 thr) per row.
__global__ __launch_bounds__(256) void ln_kernel(const float* __restrict__ x, const float* __restrict__ g,
                                                 const float* __restrict__ b, __bf16* __restrict__ out) {
  int row = blockIdx.x;
  const float* xr = x + (long)row * 768;
  float v0 = xr[threadIdx.x], v1 = xr[threadIdx.x + 256], v2 = xr[threadIdx.x + 512];
  float s = v0 + v1 + v2, s2 = v0 * v0 + v1 * v1 + v2 * v2;
#pragma unroll
  for (int m = 1; m < 64; m <<= 1) { s += __shfl_xor(s, m); s2 += __shfl_xor(s2, m); }
  __shared__ float ws1[4], ws2[4];
  int wv = threadIdx.x >> 6;
  if ((threadIdx.x & 63) == 0) { ws1[wv] = s; ws2[wv] = s2; }
  __syncthreads();
  s = ws1[0] + ws1[1] + ws1[2] + ws1[3];
  s2 = ws2[0] + ws2[1] + ws2[2] + ws2[3];
  float mu = s * (1.0f / 768.0f);
  float var = s2 * (1.0f / 768.0f) - mu * mu;
  float rstd = rsqrtf(var + 1e-5f);
  __bf16* orow = out + (long)row * 768;
  orow[threadIdx.x]       = (__bf16)((v0 - mu) * rstd * g[threadIdx.x]       + b[threadIdx.x]);
  orow[threadIdx.x + 256] = (__bf16)((v1 - mu) * rstd * g[threadIdx.x + 256] + b[threadIdx.x + 256]);
  orow[threadIdx.x + 512] = (__bf16)((v2 - mu) * rstd * g[threadIdx.x + 512] + b[threadIdx.x + 512]);
}

// ---- GEMM: 256x192 tile, BK=64, 8 waves (2M x 4N, wave tile 128x48), double-buffered,
// counted-vmcnt prefetch, T2 xor-swizzle. C[M,N] = epi(A[M,K] @ Wt[N,K]^T + bias).
// M%256==0, N%192==0, K%64==0.
template <int EPI>
__global__ __launch_bounds__(512, 2) void gemm_kernel(const __bf16* __restrict__ A, const __bf16* __restrict__ Wt,
                                                      const float* __restrict__ bias, const float* __restrict__ res,
                                                      float* __restrict__ outf, __bf16* __restrict__ outb,
                                                      int M, int N, int K) {
  __shared__ __align__(16) __bf16 Asb[2][16384];   // 256x64
  __shared__ __align__(16) __bf16 Bsb[2][12288];   // 192x64
  const int tid = threadIdx.x, lane = tid & 63, w = tid >> 6;
  const int wm = w >> 2, wn = w & 3, lr = lane & 15, lh = lane >> 4;
  const int m0 = blockIdx.y * 256, n0 = blockIdx.x * 192;
  const int nt = K >> 6;
  int srow[4], scol[4];
#pragma unroll
  for (int l = 0; l < 4; ++l) {
    int c = l * 512 + tid;
    srow[l] = c >> 3;
    scol[l] = ((c & 7) ^ ((c >> 3) & 7)) * 8;
  }
  const __bf16* Ag = A + (long)m0 * K;
  const __bf16* Bg = Wt + (long)n0 * K;
  const int ldst = w * 512;

#define STAGE(buf, t)                                                                   \
  {                                                                                     \
    int kb = (t) << 6;                                                                  \
    _Pragma("unroll") for (int l = 0; l < 4; ++l)                                       \
        async16(Ag + (long)srow[l] * K + kb + scol[l], &Asb[(buf)][l * 4096 + ldst]);   \
    _Pragma("unroll") for (int l = 0; l < 3; ++l)                                       \
        async16(Bg + (long)srow[l] * K + kb + scol[l], &Bsb[(buf)][l * 4096 + ldst]);   \
  }

  f32x4 acc[8][3] = {};
  STAGE(0, 0);
  STAGE(1, 1);
  asm volatile("s_waitcnt vmcnt(7)" ::: "memory");
  __builtin_amdgcn_s_barrier();
  __builtin_amdgcn_sched_barrier(0);

  for (int t = 0; t < nt; ++t) {
    const int buf = t & 1;
    const __bf16* As = &Asb[buf][0];
    const __bf16* Bs = &Bsb[buf][0];
    bf16x8 bfr[3][2];
#pragma unroll
    for (int n = 0; n < 3; ++n) {
      int row = wn * 48 + n * 16 + lr;
#pragma unroll
      for (int kk = 0; kk < 2; ++kk)
        bfr[n][kk] = *(const bf16x8*)&Bs[row * 64 + ((kk * 32 + lh * 8) ^ ((row & 7) << 3))];
    }
#pragma unroll
    for (int mh = 0; mh < 2; ++mh) {
      bf16x8 afr[4][2];
#pragma unroll
      for (int m4 = 0; m4 < 4; ++m4) {
        int row = wm * 128 + mh * 64 + m4 * 16 + lr;
#pragma unroll
        for (int kk = 0; kk < 2; ++kk)
          afr[m4][kk] = *(const bf16x8*)&As[row * 64 + ((kk * 32 + lh * 8) ^ ((row & 7) << 3))];
      }
      __builtin_amdgcn_s_setprio(1);
#pragma unroll
      for (int m4 = 0; m4 < 4; ++m4)
#pragma unroll
        for (int n = 0; n < 3; ++n) {
          acc[mh * 4 + m4][n] = mfma16(afr[m4][0], bfr[n][0], acc[mh * 4 + m4][n]);
          acc[mh * 4 + m4][n] = mfma16(afr[m4][1], bfr[n][1], acc[mh * 4 + m4][n]);
        }
      __builtin_amdgcn_s_setprio(0);
    }
    if (t + 1 < nt) {
      __builtin_amdgcn_sched_barrier(0);
      __builtin_amdgcn_s_barrier();
      __builtin_amdgcn_sched_barrier(0);
      if (t + 2 < nt) {
        STAGE(buf, t + 2);
        asm volatile("s_waitcnt vmcnt(7)" ::: "memory");
      } else {
        asm volatile("s_waitcnt vmcnt(0)" ::: "memory");
      }
      __builtin_amdgcn_sched_barrier(0);
      __builtin_amdgcn_s_barrier();
      __builtin_amdgcn_sched_barrier(0);
    }
  }
#undef STAGE

#pragma unroll
  for (int m = 0; m < 8; ++m)
#pragma unroll
    for (int n = 0; n < 3; ++n) {
      int col = n0 + wn * 48 + n * 16 + lr;
      float bc = bias[col];
#pragma unroll
      for (int j = 0; j < 4; ++j) {
        int row = m0 + wm * 128 + m * 16 + lh * 4 + j;
        float v = acc[m][n][j] + bc;
        if (EPI == 1) v = gelu_f(v);
        if (EPI == 2) outf[(long)row * N + col] = v + res[(long)row * N + col];
        else          outb[(long)row * N + col] = (__bf16)v;
      }
    }
}

// ---- flash attention on fused qkv buffer (rows x 2304).
// grid (192, 8): x = bz*12+h (fastest -> XCD = x%8 shared by all 8 q-tiles), y = q-tile.
// Q pre-scaled by 0.125*log2(e): softmax in exp2 domain.
__global__ __launch_bounds__(256) void attn_kernel(const __bf16* __restrict__ qkv, __bf16* __restrict__ o) {
  __shared__ __bf16 K_lds[64][72];
  __shared__ __align__(16) unsigned char Vt[8448];
  __shared__ __bf16 P_lds[4][32][72];
  const int tid = threadIdx.x;
  const int lane = tid & 63, wv = tid >> 6;
  const int lr = lane & 15, lh = lane >> 4;
  const int hb = blockIdx.x, qt = blockIdx.y;
  const int h = hb % 12, bz = hb / 12;
  const int qrow0 = bz * 1024 + qt * 128 + wv * 32;
  const int hcol = h * 64;
  const __bf16* q = qkv + hcol;
  const __bf16* k = qkv + 768 + hcol;
  const __bf16* v = qkv + 1536 + hcol;
  const float QSC = 0.18033688011112042f;  // 0.125 * log2(e)
  bf16x8 aq[2][2];
#pragma unroll
  for (int r = 0; r < 2; ++r)
#pragma unroll
    for (int kk = 0; kk < 2; ++kk) {
      bf16x8 t = *(const bf16x8*)(q + (long)(qrow0 + r * 16 + lr) * 2304 + kk * 32 + lh * 8);
#pragma unroll
      for (int e = 0; e < 8; ++e) t[e] = (__bf16)((float)t[e] * QSC);
      aq[r][kk] = t;
    }
  f32x4 o_fr[2][4] = {};
  float m_s[2][4], l_s[2][4];
#pragma unroll
  for (int r = 0; r < 2; ++r)
#pragma unroll
    for (int j = 0; j < 4; ++j) { m_s[r][j] = -1e30f; l_s[r][j] = 0.0f; }
  const int r0 = tid >> 3, c0 = (tid & 7) * 8;
  const unsigned vt0 = lds_off(Vt) + (lane >> 4) * 1056 + (lane & 15) * 2;
  const int Tst = (r0 >> 2) * 4 + (c0 >> 4);
  const int vb = Tst * 128 + (r0 & 3) * 32 + (c0 & 15) * 2 + (Tst >> 3) * 32;
  // p (kv += 32) advances the subtile index by 32 -> byte stride 32*128 + 4*32 = 4224.

  // prologue: tile 0 -> regs -> LDS
  bf16x8 rK[2], rV[2];
#pragma unroll
  for (int p = 0; p < 2; ++p) {
    long gr = (long)(bz * 1024 + p * 32 + r0) * 2304 + c0;
    rK[p] = *(const bf16x8*)(k + gr);
    rV[p] = *(const bf16x8*)(v + gr);
  }
#pragma unroll
  for (int p = 0; p < 2; ++p) {
    *(bf16x8*)&K_lds[p * 32 + r0][c0] = rK[p];
    *(bf16x8*)(Vt + vb + p * 4224) = rV[p];
  }
  __syncthreads();

  for (int t = 0; t < 16; ++t) {
    bf16x8 bk[4][2];
#pragma unroll
    for (int n = 0; n < 4; ++n)
#pragma unroll
      for (int kk = 0; kk < 2; ++kk)
        bk[n][kk] = *(const bf16x8*)&K_lds[n * 16 + lr][kk * 32 + lh * 8];
    // T14: issue next tile's global loads before the compute cluster
    if (t < 15) {
#pragma unroll
      for (int p = 0; p < 2; ++p) {
        long gr = (long)(bz * 1024 + (t + 1) * 64 + p * 32 + r0) * 2304 + c0;
        rK[p] = *(const bf16x8*)(k + gr);
        rV[p] = *(const bf16x8*)(v + gr);
      }
    }
    f32x4 sf[2][4];
    __builtin_amdgcn_s_setprio(1);
#pragma unroll
    for (int r = 0; r < 2; ++r)
#pragma unroll
      for (int n = 0; n < 4; ++n) {
        f32x4 s = {0.f, 0.f, 0.f, 0.f};
        s = mfma16(aq[r][0], bk[n][0], s);
        s = mfma16(aq[r][1], bk[n][1], s);
        sf[r][n] = s;
      }
    __builtin_amdgcn_s_setprio(0);
    float pp[2][4][4];
#pragma unroll
    for (int r = 0; r < 2; ++r) {
      float rmax[4], nm[4], rsum[4];
#pragma unroll
      for (int j = 0; j < 4; ++j)
        rmax[j] = fmaxf(fmaxf(sf[r][0][j], sf[r][1][j]), fmaxf(sf[r][2][j], sf[r][3][j]));
#pragma unroll
      for (int m = 1; m < 16; m <<= 1)
#pragma unroll
        for (int j = 0; j < 4; ++j) rmax[j] = fmaxf(rmax[j], __shfl_xor(rmax[j], m));
      // defer-max (log2 domain, THR = 8*log2e)
      bool small = rmax[0] <= m_s[r][0] + 11.54f && rmax[1] <= m_s[r][1] + 11.54f &&
                   rmax[2] <= m_s[r][2] + 11.54f && rmax[3] <= m_s[r][3] + 11.54f;
      if (!__all(small)) {
        float corr[4];
#pragma unroll
        for (int j = 0; j < 4; ++j) {
          nm[j] = fmaxf(m_s[r][j], rmax[j]);
          corr[j] = exp2f(m_s[r][j] - nm[j]);
          m_s[r][j] = nm[j];
          l_s[r][j] *= corr[j];
        }
#pragma unroll
        for (int d = 0; d < 4; ++d)
#pragma unroll
          for (int j = 0; j < 4; ++j) o_fr[r][d][j] *= corr[j];
      } else {
#pragma unroll
        for (int j = 0; j < 4; ++j) nm[j] = m_s[r][j];
      }
#pragma unroll
      for (int j = 0; j < 4; ++j) rsum[j] = 0.0f;
#pragma unroll
      for (int n = 0; n < 4; ++n)
#pragma unroll
        for (int j = 0; j < 4; ++j) {
          float pe = exp2f(sf[r][n][j] - nm[j]);
          pp[r][n][j] = pe;
          rsum[j] += pe;
        }
#pragma unroll
      for (int m = 1; m < 16; m <<= 1)
#pragma unroll
        for (int j = 0; j < 4; ++j) rsum[j] += __shfl_xor(rsum[j], m);
#pragma unroll
      for (int j = 0; j < 4; ++j) l_s[r][j] += rsum[j];
    }
#pragma unroll
    for (int r = 0; r < 2; ++r)
#pragma unroll
      for (int n = 0; n < 4; ++n)
#pragma unroll
        for (int j = 0; j < 4; ++j)
          P_lds[wv][r * 16 + lh * 4 + j][n * 16 + lr] = (__bf16)pp[r][n][j];
    u32x2 trv[4][2][2];
#pragma unroll
    for (int d0 = 0; d0 < 4; ++d0)
#pragma unroll
      for (int ks = 0; ks < 2; ++ks) {
        unsigned a = vt0 + ks * 4224 + d0 * 128;
        asm volatile("ds_read_b64_tr_b16 %0, %1" : "=v"(trv[d0][ks][0]) : "v"(a));
        asm volatile("ds_read_b64_tr_b16 %0, %1 offset:512" : "=v"(trv[d0][ks][1]) : "v"(a));
      }
    bf16x8 ap[2][2];
#pragma unroll
    for (int r = 0; r < 2; ++r)
#pragma unroll
      for (int ks = 0; ks < 2; ++ks)
        ap[r][ks] = *(const bf16x8*)&P_lds[wv][r * 16 + lr][ks * 32 + lh * 8];
    asm volatile("s_waitcnt lgkmcnt(0)");
    __builtin_amdgcn_sched_barrier(0);
    __builtin_amdgcn_s_setprio(1);
#pragma unroll
    for (int d0 = 0; d0 < 4; ++d0) {
      union { u32x2 u[2]; bf16x8 v8; } b0, b1;
      b0.u[0] = trv[d0][0][0]; b0.u[1] = trv[d0][0][1];
      b1.u[0] = trv[d0][1][0]; b1.u[1] = trv[d0][1][1];
#pragma unroll
      for (int r = 0; r < 2; ++r) {
        o_fr[r][d0] = mfma16(ap[r][0], b0.v8, o_fr[r][d0]);
        o_fr[r][d0] = mfma16(ap[r][1], b1.v8, o_fr[r][d0]);
      }
    }
    __builtin_amdgcn_s_setprio(0);
    __syncthreads();           // all waves done with K_lds/Vt of tile t
    if (t < 15) {
#pragma unroll
      for (int p = 0; p < 2; ++p) {
        *(bf16x8*)&K_lds[p * 32 + r0][c0] = rK[p];
        *(bf16x8*)(Vt + vb + p * 4224) = rV[p];
      }
      __syncthreads();
    }
  }
#pragma unroll
  for (int r = 0; r < 2; ++r)
#pragma unroll
    for (int d = 0; d < 4; ++d)
#pragma unroll
      for (int j = 0; j < 4; ++j) {
        int row = qrow0 + r * 16 + lh * 4 + j;
        int col = hcol + d * 16 + lr;
        o[(long)row * 768 + col] = (__bf16)(o_fr[r][d][j] * (1.0f / l_s[r][j]));
      }
}

extern "C" void kernel_launch(void* const* d_in, const int* in_sizes, int n_in,
                              void* d_out, int out_size, void* d_ws, size_t ws_size,
                              hipStream_t stream) {
  const float* x    = (const float*)d_in[0];
  const float* ln1g = (const float*)d_in[1];
  const float* ln1b = (const float*)d_in[2];
  const float* wq   = (const float*)d_in[3];
  const float* bq   = (const float*)d_in[4];
  const float* wk   = (const float*)d_in[5];
  const float* bk   = (const float*)d_in[6];
  const float* wv   = (const float*)d_in[7];
  const float* bv   = (const float*)d_in[8];
  const float* wo   = (const float*)d_in[9];
  const float* bo   = (const float*)d_in[10];
  const float* ln2g = (const float*)d_in[11];
  const float* ln2b = (const float*)d_in[12];
  const float* w1   = (const float*)d_in[13];
  const float* b1   = (const float*)d_in[14];
  const float* w2   = (const float*)d_in[15];
  const float* b2   = (const float*)d_in[16];
  float* out = (float*)d_out;
  char* ws = (char*)d_ws;

  const long SD = 16384L * 768;
  const long SF = 16384L * 3072;

  __bf16* qkv = (__bf16*)(ws);                      // 16384 x 2304
  __bf16* f1  = (__bf16*)(ws);                      // aliases qkv (dead by FFN1)
  __bf16* hb  = (__bf16*)(ws + 2 * SF);             // LN1 out; later attn out
  float*  x2  = (float*)(ws + 2 * SF + 2 * SD);
  __bf16* h2  = (__bf16*)(ws + 2 * SF + 2 * SD + 4 * SD);
  __bf16* wtqkv = (__bf16*)(ws + 2 * SF + 2 * SD + 4 * SD + 2 * SD);  // 2304 x 768
  __bf16* wto = wtqkv + 2304L * 768;
  __bf16* wt1 = wto + 768L * 768;
  __bf16* wt2 = wt1 + 768L * 3072;
  float*  bqkv = (float*)(wt2 + 3072L * 768);

  wprep_qkv_kernel<<<(2304 * 768 + 255) / 256, 256, 0, stream>>>(wq, wk, wv, wtqkv);
  wprep_kernel<<<(768 * 768 + 255) / 256, 256, 0, stream>>>(wo, wto, 768, 768);
  wprep_kernel<<<(768 * 3072 + 255) / 256, 256, 0, stream>>>(w1, wt1, 768, 3072);
  wprep_kernel<<<(768 * 3072 + 255) / 256, 256, 0, stream>>>(w2, wt2, 3072, 768);
  bias_cat_kernel<<<9, 256, 0, stream>>>(bq, bk, bv, bqkv);

  ln_kernel<<<16384, 256, 0, stream>>>(x, ln1g, ln1b, hb);
  gemm_kernel<0><<<dim3(12, 64), 512, 0, stream>>>(hb, wtqkv, bqkv, nullptr, nullptr, qkv, 16384, 2304, 768);
  attn_kernel<<<dim3(192, 8), 256, 0, stream>>>(qkv, hb);
  gemm_kernel<2><<<dim3(4, 64), 512, 0, stream>>>(hb, wto, bo, x, x2, nullptr, 16384, 768, 768);
  ln_kernel<<<16384, 256, 0, stream>>>(x2, ln2g, ln2b, h2);
  gemm_kernel<1><<<dim3(16, 64), 512, 0, stream>>>(h2, wt1, b1, nullptr, nullptr, f1, 16384, 3072, 768);
  gemm_kernel<2><<<dim3(4, 64), 512, 0, stream>>>(f1, wt2, b2, x2, out, nullptr, 16384, 768, 3072);
}

// Round 6
// 563.479 us; speedup vs baseline: 1.1520x; 1.1520x over previous
//
#include <hip/hip_runtime.h>
#include <hip/hip_bf16.h>
#include <math.h>

typedef __bf16 bf16x8 __attribute__((ext_vector_type(8)));
typedef float f32x4 __attribute__((ext_vector_type(4)));
typedef unsigned int u32x2 __attribute__((ext_vector_type(2)));

__device__ __forceinline__ f32x4 mfma16(bf16x8 a, bf16x8 b, f32x4 c) {
  return __builtin_amdgcn_mfma_f32_16x16x32_bf16(a, b, c, 0, 0, 0);
}

__device__ __forceinline__ float gelu_f(float v) {
  return 0.5f * v * (1.0f + erff(v * 0.70710678118654752f));
}

__device__ __forceinline__ void async16(const void* g, void* l) {
  __builtin_amdgcn_global_load_lds((const __attribute__((address_space(1))) unsigned int*)g,
                                   (__attribute__((address_space(3))) unsigned int*)l, 16, 0, 0);
}

__device__ __forceinline__ unsigned lds_off(const void* p) {
  return (unsigned)(unsigned long long)(const __attribute__((address_space(3))) void*)p;
}

// ---- weight convert + transpose: Wt[n][k] = (bf16) W[k][n];  W is K x N row-major
__global__ void wprep_kernel(const float* __restrict__ W, __bf16* __restrict__ Wt, int K, int N) {
  long i = (long)blockIdx.x * 256 + threadIdx.x;
  if (i >= (long)K * N) return;
  int k = (int)(i % K), n = (int)(i / K);
  Wt[i] = (__bf16)W[(long)k * N + n];
}

__global__ void wprep_qkv_kernel(const float* __restrict__ Wq, const float* __restrict__ Wk,
                                 const float* __restrict__ Wv, __bf16* __restrict__ Wt) {
  long i = (long)blockIdx.x * 256 + threadIdx.x;
  if (i >= 2304L * 768) return;
  int k = (int)(i % 768), n = (int)(i / 768);
  const float* W = (n < 768) ? Wq : (n < 1536) ? Wk : Wv;
  Wt[i] = (__bf16)W[(long)k * 768 + (n % 768)];
}

__global__ void bias_cat_kernel(const float* __restrict__ bq, const float* __restrict__ bk,
                                const float* __restrict__ bv, float* __restrict__ o) {
  int i = blockIdx.x * 256 + threadIdx.x;
  if (i >= 2304) return;
  o[i] = (i < 768) ? bq[i] : (i < 1536) ? bk[i - 768] : bv[i - 1536];
}

// ---- layernorm: fp32 in (rows x 768), bf16 out. One block (256 thr) per row.
__global__ __launch_bounds__(256) void ln_kernel(const float* __restrict__ x, const float* __restrict__ g,
                                                 const float* __restrict__ b, __bf16* __restrict__ out) {
  int row = blockIdx.x;
  const float* xr = x + (long)row * 768;
  float v0 = xr[threadIdx.x], v1 = xr[threadIdx.x + 256], v2 = xr[threadIdx.x + 512];
  float s = v0 + v1 + v2, s2 = v0 * v0 + v1 * v1 + v2 * v2;
#pragma unroll
  for (int m = 1; m < 64; m <<= 1) { s += __shfl_xor(s, m); s2 += __shfl_xor(s2, m); }
  __shared__ float ws1[4], ws2[4];
  int wv = threadIdx.x >> 6;
  if ((threadIdx.x & 63) == 0) { ws1[wv] = s; ws2[wv] = s2; }
  __syncthreads();
  s = ws1[0] + ws1[1] + ws1[2] + ws1[3];
  s2 = ws2[0] + ws2[1] + ws2[2] + ws2[3];
  float mu = s * (1.0f / 768.0f);
  float var = s2 * (1.0f / 768.0f) - mu * mu;
  float rstd = rsqrtf(var + 1e-5f);
  __bf16* orow = out + (long)row * 768;
  orow[threadIdx.x]       = (__bf16)((v0 - mu) * rstd * g[threadIdx.x]       + b[threadIdx.x]);
  orow[threadIdx.x + 256] = (__bf16)((v1 - mu) * rstd * g[threadIdx.x + 256] + b[threadIdx.x + 256]);
  orow[threadIdx.x + 512] = (__bf16)((v2 - mu) * rstd * g[threadIdx.x + 512] + b[threadIdx.x + 512]);
}

// ---- GEMM: 256x192 tile, BK=64, 8 waves (2M x 4N, wave tile 128x48), double-buffered,
// counted-vmcnt prefetch, T2 xor-swizzle. C[M,N] = epi(A[M,K] @ Wt[N,K]^T + bias).
// M%256==0, N%192==0, K%64==0.
template <int EPI>
__global__ __launch_bounds__(512, 2) void gemm_kernel(const __bf16* __restrict__ A, const __bf16* __restrict__ Wt,
                                                      const float* __restrict__ bias, const float* __restrict__ res,
                                                      float* __restrict__ outf, __bf16* __restrict__ outb,
                                                      int M, int N, int K) {
  __shared__ __align__(16) __bf16 Asb[2][16384];   // 256x64
  __shared__ __align__(16) __bf16 Bsb[2][12288];   // 192x64
  const int tid = threadIdx.x, lane = tid & 63, w = tid >> 6;
  const int wm = w >> 2, wn = w & 3, lr = lane & 15, lh = lane >> 4;
  const int m0 = blockIdx.y * 256, n0 = blockIdx.x * 192;
  const int nt = K >> 6;
  int srow[4], scol[4];
#pragma unroll
  for (int l = 0; l < 4; ++l) {
    int c = l * 512 + tid;
    srow[l] = c >> 3;
    scol[l] = ((c & 7) ^ ((c >> 3) & 7)) * 8;
  }
  const __bf16* Ag = A + (long)m0 * K;
  const __bf16* Bg = Wt + (long)n0 * K;
  const int ldst = w * 512;

#define STAGE(buf, t)                                                                   \
  {                                                                                     \
    int kb = (t) << 6;                                                                  \
    _Pragma("unroll") for (int l = 0; l < 4; ++l)                                       \
        async16(Ag + (long)srow[l] * K + kb + scol[l], &Asb[(buf)][l * 4096 + ldst]);   \
    _Pragma("unroll") for (int l = 0; l < 3; ++l)                                       \
        async16(Bg + (long)srow[l] * K + kb + scol[l], &Bsb[(buf)][l * 4096 + ldst]);   \
  }

  f32x4 acc[8][3] = {};
  STAGE(0, 0);
  STAGE(1, 1);
  asm volatile("s_waitcnt vmcnt(7)" ::: "memory");
  __builtin_amdgcn_s_barrier();
  __builtin_amdgcn_sched_barrier(0);

  for (int t = 0; t < nt; ++t) {
    const int buf = t & 1;
    const __bf16* As = &Asb[buf][0];
    const __bf16* Bs = &Bsb[buf][0];
    bf16x8 bfr[3][2];
#pragma unroll
    for (int n = 0; n < 3; ++n) {
      int row = wn * 48 + n * 16 + lr;
#pragma unroll
      for (int kk = 0; kk < 2; ++kk)
        bfr[n][kk] = *(const bf16x8*)&Bs[row * 64 + ((kk * 32 + lh * 8) ^ ((row & 7) << 3))];
    }
#pragma unroll
    for (int mh = 0; mh < 2; ++mh) {
      bf16x8 afr[4][2];
#pragma unroll
      for (int m4 = 0; m4 < 4; ++m4) {
        int row = wm * 128 + mh * 64 + m4 * 16 + lr;
#pragma unroll
        for (int kk = 0; kk < 2; ++kk)
          afr[m4][kk] = *(const bf16x8*)&As[row * 64 + ((kk * 32 + lh * 8) ^ ((row & 7) << 3))];
      }
      __builtin_amdgcn_s_setprio(1);
#pragma unroll
      for (int m4 = 0; m4 < 4; ++m4)
#pragma unroll
        for (int n = 0; n < 3; ++n) {
          acc[mh * 4 + m4][n] = mfma16(afr[m4][0], bfr[n][0], acc[mh * 4 + m4][n]);
          acc[mh * 4 + m4][n] = mfma16(afr[m4][1], bfr[n][1], acc[mh * 4 + m4][n]);
        }
      __builtin_amdgcn_s_setprio(0);
    }
    if (t + 1 < nt) {
      __builtin_amdgcn_sched_barrier(0);
      __builtin_amdgcn_s_barrier();
      __builtin_amdgcn_sched_barrier(0);
      if (t + 2 < nt) {
        STAGE(buf, t + 2);
        asm volatile("s_waitcnt vmcnt(7)" ::: "memory");
      } else {
        asm volatile("s_waitcnt vmcnt(0)" ::: "memory");
      }
      __builtin_amdgcn_sched_barrier(0);
      __builtin_amdgcn_s_barrier();
      __builtin_amdgcn_sched_barrier(0);
    }
  }
#undef STAGE

#pragma unroll
  for (int m = 0; m < 8; ++m)
#pragma unroll
    for (int n = 0; n < 3; ++n) {
      int col = n0 + wn * 48 + n * 16 + lr;
      float bc = bias[col];
#pragma unroll
      for (int j = 0; j < 4; ++j) {
        int row = m0 + wm * 128 + m * 16 + lh * 4 + j;
        float v = acc[m][n][j] + bc;
        if (EPI == 1) v = gelu_f(v);
        if (EPI == 2) outf[(long)row * N + col] = v + res[(long)row * N + col];
        else          outb[(long)row * N + col] = (__bf16)v;
      }
    }
}

// ---- flash attention on fused qkv buffer (rows x 2304).
// grid (192, 8): x = bz*12+h (fastest -> XCD = x%8 shared by all 8 q-tiles), y = q-tile.
// Q pre-scaled by 0.125*log2(e): softmax in exp2 domain (v_exp_f32 via builtin).
// Fast path: m_s stays 0, no cross-lane max (local guard + __all); l via MFMA ones-trick.
__global__ __launch_bounds__(256) void attn_kernel(const __bf16* __restrict__ qkv, __bf16* __restrict__ o) {
  __shared__ __bf16 K_lds[64][72];
  __shared__ __align__(16) unsigned char Vt[8448];
  __shared__ __bf16 P_lds[4][32][72];
  const int tid = threadIdx.x;
  const int lane = tid & 63, wv = tid >> 6;
  const int lr = lane & 15, lh = lane >> 4;
  const int hb = blockIdx.x, qt = blockIdx.y;
  const int h = hb % 12, bz = hb / 12;
  const int qrow0 = bz * 1024 + qt * 128 + wv * 32;
  const int hcol = h * 64;
  const __bf16* q = qkv + hcol;
  const __bf16* k = qkv + 768 + hcol;
  const __bf16* v = qkv + 1536 + hcol;
  const float QSC = 0.18033688011112042f;  // 0.125 * log2(e)
  bf16x8 aq[2][2];
#pragma unroll
  for (int r = 0; r < 2; ++r)
#pragma unroll
    for (int kk = 0; kk < 2; ++kk) {
      bf16x8 t = *(const bf16x8*)(q + (long)(qrow0 + r * 16 + lr) * 2304 + kk * 32 + lh * 8);
#pragma unroll
      for (int e = 0; e < 8; ++e) t[e] = (__bf16)((float)t[e] * QSC);
      aq[r][kk] = t;
    }
  bf16x8 ones;
#pragma unroll
  for (int e = 0; e < 8; ++e) ones[e] = (__bf16)1.0f;
  f32x4 o_fr[2][4] = {};
  float m_s[2][4], l_s[2][4];
#pragma unroll
  for (int r = 0; r < 2; ++r)
#pragma unroll
    for (int j = 0; j < 4; ++j) { m_s[r][j] = 0.0f; l_s[r][j] = 0.0f; }
  const int r0 = tid >> 3, c0 = (tid & 7) * 8;
  const unsigned vt0 = lds_off(Vt) + (lane >> 4) * 1056 + (lane & 15) * 2;
  const int Tst = (r0 >> 2) * 4 + (c0 >> 4);
  const int vb = Tst * 128 + (r0 & 3) * 32 + (c0 & 15) * 2 + (Tst >> 3) * 32;
  // p (kv += 32) advances the subtile index by 32 -> byte stride 32*128 + 4*32 = 4224.

  // prologue: tile 0 -> regs -> LDS
  bf16x8 rK[2], rV[2];
#pragma unroll
  for (int p = 0; p < 2; ++p) {
    long gr = (long)(bz * 1024 + p * 32 + r0) * 2304 + c0;
    rK[p] = *(const bf16x8*)(k + gr);
    rV[p] = *(const bf16x8*)(v + gr);
  }
#pragma unroll
  for (int p = 0; p < 2; ++p) {
    *(bf16x8*)&K_lds[p * 32 + r0][c0] = rK[p];
    *(bf16x8*)(Vt + vb + p * 4224) = rV[p];
  }
  __syncthreads();

  for (int t = 0; t < 16; ++t) {
    bf16x8 bk[4][2];
#pragma unroll
    for (int n = 0; n < 4; ++n)
#pragma unroll
      for (int kk = 0; kk < 2; ++kk)
        bk[n][kk] = *(const bf16x8*)&K_lds[n * 16 + lr][kk * 32 + lh * 8];
    // T14: issue next tile's global loads before the compute cluster
    if (t < 15) {
#pragma unroll
      for (int p = 0; p < 2; ++p) {
        long gr = (long)(bz * 1024 + (t + 1) * 64 + p * 32 + r0) * 2304 + c0;
        rK[p] = *(const bf16x8*)(k + gr);
        rV[p] = *(const bf16x8*)(v + gr);
      }
    }
    f32x4 sf[2][4];
    __builtin_amdgcn_s_setprio(1);
#pragma unroll
    for (int r = 0; r < 2; ++r)
#pragma unroll
      for (int n = 0; n < 4; ++n) {
        f32x4 s = {0.f, 0.f, 0.f, 0.f};
        s = mfma16(aq[r][0], bk[n][0], s);
        s = mfma16(aq[r][1], bk[n][1], s);
        sf[r][n] = s;
      }
    __builtin_amdgcn_s_setprio(0);
    // ---- softmax (log2 domain). Fast path: lane-local bound check only.
    float pp[2][4][4];
    bool ok = true;
#pragma unroll
    for (int r = 0; r < 2; ++r)
#pragma unroll
      for (int j = 0; j < 4; ++j) {
        float lm = fmaxf(fmaxf(sf[r][0][j], sf[r][1][j]), fmaxf(sf[r][2][j], sf[r][3][j]));
        ok = ok && (lm <= m_s[r][j] + 11.54f);
      }
    if (!__all(ok)) {
      // slow path (rare): true row-max via shfl, rescale
#pragma unroll
      for (int r = 0; r < 2; ++r) {
        float rmax[4];
#pragma unroll
        for (int j = 0; j < 4; ++j)
          rmax[j] = fmaxf(fmaxf(sf[r][0][j], sf[r][1][j]), fmaxf(sf[r][2][j], sf[r][3][j]));
#pragma unroll
        for (int m = 1; m < 16; m <<= 1)
#pragma unroll
          for (int j = 0; j < 4; ++j) rmax[j] = fmaxf(rmax[j], __shfl_xor(rmax[j], m));
#pragma unroll
        for (int j = 0; j < 4; ++j) {
          float nm = fmaxf(m_s[r][j], rmax[j]);
          float corr = __builtin_amdgcn_exp2f(m_s[r][j] - nm);
          m_s[r][j] = nm;
          l_s[r][j] *= corr;
#pragma unroll
          for (int d = 0; d < 4; ++d) o_fr[r][d][j] *= corr;
        }
      }
    }
#pragma unroll
    for (int r = 0; r < 2; ++r)
#pragma unroll
      for (int n = 0; n < 4; ++n)
#pragma unroll
        for (int j = 0; j < 4; ++j)
          pp[r][n][j] = __builtin_amdgcn_exp2f(sf[r][n][j] - m_s[r][j]);
#pragma unroll
    for (int r = 0; r < 2; ++r)
#pragma unroll
      for (int n = 0; n < 4; ++n)
#pragma unroll
        for (int j = 0; j < 4; ++j)
          P_lds[wv][r * 16 + lh * 4 + j][n * 16 + lr] = (__bf16)pp[r][n][j];
    u32x2 trv[4][2][2];
#pragma unroll
    for (int d0 = 0; d0 < 4; ++d0)
#pragma unroll
      for (int ks = 0; ks < 2; ++ks) {
        unsigned a = vt0 + ks * 4224 + d0 * 128;
        asm volatile("ds_read_b64_tr_b16 %0, %1" : "=v"(trv[d0][ks][0]) : "v"(a));
        asm volatile("ds_read_b64_tr_b16 %0, %1 offset:512" : "=v"(trv[d0][ks][1]) : "v"(a));
      }
    bf16x8 ap[2][2];
#pragma unroll
    for (int r = 0; r < 2; ++r)
#pragma unroll
      for (int ks = 0; ks < 2; ++ks)
        ap[r][ks] = *(const bf16x8*)&P_lds[wv][r * 16 + lr][ks * 32 + lh * 8];
    asm volatile("s_waitcnt lgkmcnt(0)");
    __builtin_amdgcn_sched_barrier(0);
    __builtin_amdgcn_s_setprio(1);
    // l accumulation via MFMA ones-trick: row-sum of P lands at (lh*4+j) = this lane's rows
#pragma unroll
    for (int r = 0; r < 2; ++r) {
      f32x4 ls = {0.f, 0.f, 0.f, 0.f};
      ls = mfma16(ap[r][0], ones, ls);
      ls = mfma16(ap[r][1], ones, ls);
#pragma unroll
      for (int j = 0; j < 4; ++j) l_s[r][j] += ls[j];
    }
#pragma unroll
    for (int d0 = 0; d0 < 4; ++d0) {
      union { u32x2 u[2]; bf16x8 v8; } b0, b1;
      b0.u[0] = trv[d0][0][0]; b0.u[1] = trv[d0][0][1];
      b1.u[0] = trv[d0][1][0]; b1.u[1] = trv[d0][1][1];
#pragma unroll
      for (int r = 0; r < 2; ++r) {
        o_fr[r][d0] = mfma16(ap[r][0], b0.v8, o_fr[r][d0]);
        o_fr[r][d0] = mfma16(ap[r][1], b1.v8, o_fr[r][d0]);
      }
    }
    __builtin_amdgcn_s_setprio(0);
    __syncthreads();           // all waves done with K_lds/Vt of tile t
    if (t < 15) {
#pragma unroll
      for (int p = 0; p < 2; ++p) {
        *(bf16x8*)&K_lds[p * 32 + r0][c0] = rK[p];
        *(bf16x8*)(Vt + vb + p * 4224) = rV[p];
      }
      __syncthreads();
    }
  }
#pragma unroll
  for (int r = 0; r < 2; ++r)
#pragma unroll
    for (int d = 0; d < 4; ++d)
#pragma unroll
      for (int j = 0; j < 4; ++j) {
        int row = qrow0 + r * 16 + lh * 4 + j;
        int col = hcol + d * 16 + lr;
        o[(long)row * 768 + col] = (__bf16)(o_fr[r][d][j] * (1.0f / l_s[r][j]));
      }
}

extern "C" void kernel_launch(void* const* d_in, const int* in_sizes, int n_in,
                              void* d_out, int out_size, void* d_ws, size_t ws_size,
                              hipStream_t stream) {
  const float* x    = (const float*)d_in[0];
  const float* ln1g = (const float*)d_in[1];
  const float* ln1b = (const float*)d_in[2];
  const float* wq   = (const float*)d_in[3];
  const float* bq   = (const float*)d_in[4];
  const float* wk   = (const float*)d_in[5];
  const float* bk   = (const float*)d_in[6];
  const float* wv   = (const float*)d_in[7];
  const float* bv   = (const float*)d_in[8];
  const float* wo   = (const float*)d_in[9];
  const float* bo   = (const float*)d_in[10];
  const float* ln2g = (const float*)d_in[11];
  const float* ln2b = (const float*)d_in[12];
  const float* w1   = (const float*)d_in[13];
  const float* b1   = (const float*)d_in[14];
  const float* w2   = (const float*)d_in[15];
  const float* b2   = (const float*)d_in[16];
  float* out = (float*)d_out;
  char* ws = (char*)d_ws;

  const long SD = 16384L * 768;
  const long SF = 16384L * 3072;

  __bf16* qkv = (__bf16*)(ws);                      // 16384 x 2304
  __bf16* f1  = (__bf16*)(ws);                      // aliases qkv (dead by FFN1)
  __bf16* hb  = (__bf16*)(ws + 2 * SF);             // LN1 out; later attn out
  float*  x2  = (float*)(ws + 2 * SF + 2 * SD);
  __bf16* h2  = (__bf16*)(ws + 2 * SF + 2 * SD + 4 * SD);
  __bf16* wtqkv = (__bf16*)(ws + 2 * SF + 2 * SD + 4 * SD + 2 * SD);  // 2304 x 768
  __bf16* wto = wtqkv + 2304L * 768;
  __bf16* wt1 = wto + 768L * 768;
  __bf16* wt2 = wt1 + 768L * 3072;
  float*  bqkv = (float*)(wt2 + 3072L * 768);

  wprep_qkv_kernel<<<(2304 * 768 + 255) / 256, 256, 0, stream>>>(wq, wk, wv, wtqkv);
  wprep_kernel<<<(768 * 768 + 255) / 256, 256, 0, stream>>>(wo, wto, 768, 768);
  wprep_kernel<<<(768 * 3072 + 255) / 256, 256, 0, stream>>>(w1, wt1, 768, 3072);
  wprep_kernel<<<(768 * 3072 + 255) / 256, 256, 0, stream>>>(w2, wt2, 3072, 768);
  bias_cat_kernel<<<9, 256, 0, stream>>>(bq, bk, bv, bqkv);

  ln_kernel<<<16384, 256, 0, stream>>>(x, ln1g, ln1b, hb);
  gemm_kernel<0><<<dim3(12, 64), 512, 0, stream>>>(hb, wtqkv, bqkv, nullptr, nullptr, qkv, 16384, 2304, 768);
  attn_kernel<<<dim3(192, 8), 256, 0, stream>>>(qkv, hb);
  gemm_kernel<2><<<dim3(4, 64), 512, 0, stream>>>(hb, wto, bo, x, x2, nullptr, 16384, 768, 768);
  ln_kernel<<<16384, 256, 0, stream>>>(x2, ln2g, ln2b, h2);
  gemm_kernel<1><<<dim3(16, 64), 512, 0, stream>>>(h2, wt1, b1, nullptr, nullptr, f1, 16384, 3072, 768);
  gemm_kernel<2><<<dim3(4, 64), 512, 0, stream>>>(f1, wt2, b2, x2, out, nullptr, 16384, 768, 3072);
}